// Round 6
// baseline (179.088 us; speedup 1.0000x reference)
//
#include <hip/hip_runtime.h>
#include <math.h>

#define B_ 32
#define S_ 4096
#define H_ 1024

// ---- pass1 geometry ----
// Per batch: 64 blocks; block blk owns rows {blk + 64*j, j=0..63} (strided
// interleave -> all blocks of a batch sweep ONE contiguous 256-row band).
// Wave w of a block: j = w + 4*t, t=0..15.
#define NBLK  64                // blocks per batch
#define RPW   16                // rows per wave

typedef float f32x4 __attribute__((ext_vector_type(4)));
__device__ __forceinline__ float4 ntload(const float4* p) {
    f32x4 v = __builtin_nontemporal_load(reinterpret_cast<const f32x4*>(p));
    union { f32x4 a; float4 b; } u; u.a = v; return u.b;
}

__device__ __forceinline__ float wave_reduce_sum(float v) {
    #pragma unroll
    for (int o = 32; o > 0; o >>= 1) v += __shfl_xor(v, o, 64);
    return v;
}

__device__ __forceinline__ void wave_reduce_sum2(float& a, float& b) {
    #pragma unroll
    for (int o = 32; o > 0; o >>= 1) {
        a += __shfl_xor(a, o, 64);
        b += __shfl_xor(b, o, 64);
    }
}

// y[b*ystride + i0..i0+7] per wave; x cached in regs, W read exactly once.
__global__ __launch_bounds__(256) void gemv_aw(const float* __restrict__ x, int xstride,
                                               const float* __restrict__ W,
                                               const float* __restrict__ bias,
                                               float* __restrict__ y, int ystride) {
    int w = threadIdx.x >> 6, lane = threadIdx.x & 63;
    int gw = blockIdx.x * 4 + w;            // [0, B*128)
    int b = gw >> 7;
    int i0 = (gw & 127) << 3;
    const float4* xr = reinterpret_cast<const float4*>(x + (size_t)b * xstride);
    float4 xv[4];
    #pragma unroll
    for (int k = 0; k < 4; ++k) xv[k] = xr[lane + k * 64];
    #pragma unroll
    for (int j = 0; j < 8; j += 2) {
        const float4* w0 = reinterpret_cast<const float4*>(W + (size_t)(i0 + j) * H_);
        const float4* w1 = reinterpret_cast<const float4*>(W + (size_t)(i0 + j + 1) * H_);
        float s0 = 0.f, s1 = 0.f;
        #pragma unroll
        for (int k = 0; k < 4; ++k) {
            float4 a = w0[lane + k * 64], c = w1[lane + k * 64];
            s0 += a.x * xv[k].x + a.y * xv[k].y + a.z * xv[k].z + a.w * xv[k].w;
            s1 += c.x * xv[k].x + c.y * xv[k].y + c.z * xv[k].z + c.w * xv[k].w;
        }
        wave_reduce_sum2(s0, s1);
        if (lane == 0) {
            y[(size_t)b * ystride + i0 + j]     = s0 + bias[i0 + j];
            y[(size_t)b * ystride + i0 + j + 1] = s1 + bias[i0 + j + 1];
        }
    }
}

// load one row (phase index t in the wave's 16-row sequence) into dst
// row = blk + 64*(w + 4*t)  ->  float4 offset = t * 256rows * 256f4 = t*65536
#define LOADROW1(dst, t) do {                                                    \
    const float4* rp_ = base + (size_t)(t) * 65536;                              \
    dst[0] = ntload(rp_);       dst[1] = ntload(rp_ + 64);                       \
    dst[2] = ntload(rp_ + 128); dst[3] = ntload(rp_ + 192);                      \
} while (0)

#define PROCESS1(va, t) do {                                                     \
    float s_ = 0.f;                                                              \
    _Pragma("unroll")                                                            \
    for (int k = 0; k < 4; ++k)                                                  \
        s_ += va[k].x * hv[k].x + va[k].y * hv[k].y + va[k].z * hv[k].z + va[k].w * hv[k].w; \
    s_ = wave_reduce_sum(s_);                                                    \
    my_score = (lane == (t)) ? s_ : my_score;                                    \
    if (s_ > m) {                       /* wave-uniform */                       \
        float sc_ = __expf(m - s_);     /* m=-inf first time -> 0, exact */      \
        l *= sc_;                                                                \
        _Pragma("unroll")                                                        \
        for (int k = 0; k < 4; ++k) {                                            \
            acc[k].x *= sc_; acc[k].y *= sc_; acc[k].z *= sc_; acc[k].w *= sc_;  \
        }                                                                        \
        m = s_;                                                                  \
    }                                                                            \
    float p_ = __expf(s_ - m);                                                   \
    l += p_;                                                                     \
    _Pragma("unroll")                                                            \
    for (int k = 0; k < 4; ++k) {                                                \
        acc[k].x += p_ * va[k].x;                                                \
        acc[k].y += p_ * va[k].y;                                                \
        acc[k].z += p_ * va[k].z;                                                \
        acc[k].w += p_ * va[k].w;                                                \
    }                                                                            \
} while (0)

// Flash pass over enc. Strided-row assignment (compact per-batch memory front),
// nontemporal loads (no L2 retention for the 512MB zero-reuse stream),
// single-row quad-buffer at 4 blocks/CU -> 2048 blocks = exactly 2 rounds.
__global__ __launch_bounds__(256, 4) void attn_pass1(const float* __restrict__ enc,
                                                     const float* __restrict__ h2,
                                                     float* __restrict__ scores,
                                                     float* __restrict__ partials) {
    int b   = blockIdx.x >> 6;              // 64 blocks per batch
    int blk = blockIdx.x & (NBLK - 1);
    int w = threadIdx.x >> 6, lane = threadIdx.x & 63;

    // wave w starts at row blk + 64*w; advances 256 rows per phase t
    const float4* base = reinterpret_cast<const float4*>(
        enc + (size_t)b * S_ * H_ + (size_t)(blk + 64 * w) * H_) + lane;

    const float4* hp = reinterpret_cast<const float4*>(h2 + (size_t)b * H_);
    float4 hv[4];
    #pragma unroll
    for (int k = 0; k < 4; ++k) hv[k] = hp[lane + k * 64];

    float m = -INFINITY, l = 0.f;
    float4 acc[4];
    #pragma unroll
    for (int k = 0; k < 4; ++k) acc[k] = make_float4(0.f, 0.f, 0.f, 0.f);
    float my_score = 0.f;                   // lane t keeps phase-t row's score

    float4 A[4], B[4], C[4], D[4];
    LOADROW1(A, 0); LOADROW1(B, 1); LOADROW1(C, 2); LOADROW1(D, 3);

    #pragma unroll 1
    for (int t = 0; t < RPW; t += 4) {
        PROCESS1(A, t);     if (t + 4 < RPW) LOADROW1(A, t + 4);
        PROCESS1(B, t + 1); if (t + 5 < RPW) LOADROW1(B, t + 5);
        PROCESS1(C, t + 2); if (t + 6 < RPW) LOADROW1(C, t + 6);
        PROCESS1(D, t + 3); if (t + 7 < RPW) LOADROW1(D, t + 7);
    }
    // lane t (t<16) holds score of row blk + 64*(w + 4*t)
    if (lane < RPW) scores[(size_t)b * S_ + blk + 64 * (w + 4 * lane)] = my_score;

    // 4-wave merge in LDS
    __shared__ float lds_ctx[4][H_];
    __shared__ float lds_m[4], lds_l[4];
    float4* mc = reinterpret_cast<float4*>(&lds_ctx[w][0]);
    #pragma unroll
    for (int k = 0; k < 4; ++k) mc[lane + k * 64] = acc[k];
    if (lane == 0) { lds_m[w] = m; lds_l[w] = l; }
    __syncthreads();

    float mb = fmaxf(fmaxf(lds_m[0], lds_m[1]), fmaxf(lds_m[2], lds_m[3]));
    float sc0 = __expf(lds_m[0] - mb), sc1 = __expf(lds_m[1] - mb);
    float sc2 = __expf(lds_m[2] - mb), sc3 = __expf(lds_m[3] - mb);
    float lb = lds_l[0] * sc0 + lds_l[1] * sc1 + lds_l[2] * sc2 + lds_l[3] * sc3;

    float* part = partials + ((size_t)b * NBLK + blk) * (H_ + 2);
    #pragma unroll
    for (int k2 = 0; k2 < 4; ++k2) {
        int col = threadIdx.x + k2 * 256;
        float v = lds_ctx[0][col] * sc0 + lds_ctx[1][col] * sc1 +
                  lds_ctx[2][col] * sc2 + lds_ctx[3][col] * sc3;
        part[2 + col] = v;
    }
    if (threadIdx.x == 0) { part[0] = mb; part[1] = lb; }
}

// per-batch reduce of NBLK partials -> normalized context + fused attn write.
__global__ __launch_bounds__(256) void attn_reduce(const float* __restrict__ partials,
                                                   float* __restrict__ concat,
                                                   const float* __restrict__ scores,
                                                   float* __restrict__ attn_out) {
    int b = blockIdx.x >> 2;
    int q = blockIdx.x & 3;
    const float* part = partials + (size_t)b * NBLK * (H_ + 2);
    __shared__ float s_m[NBLK], s_l[NBLK], s_sc[NBLK];
    int t = threadIdx.x;
    if (t < NBLK) {
        s_m[t] = part[(size_t)t * (H_ + 2)];
        s_l[t] = part[(size_t)t * (H_ + 2) + 1];
    }
    __syncthreads();
    float mb = -INFINITY;
    #pragma unroll
    for (int k = 0; k < NBLK; ++k) mb = fmaxf(mb, s_m[k]);
    if (t < NBLK) s_sc[t] = __expf(s_m[t] - mb);
    __syncthreads();
    float lb = 0.f;
    #pragma unroll
    for (int k = 0; k < NBLK; ++k) lb += s_l[k] * s_sc[k];
    float inv_l = 1.f / lb;
    int col = q * 256 + t;
    float v = 0.f;
    #pragma unroll 8
    for (int k = 0; k < NBLK; ++k)
        v += part[(size_t)k * (H_ + 2) + 2 + col] * s_sc[k];
    concat[(size_t)b * 2048 + 1024 + col] = v * inv_l;

    const float4* sp = reinterpret_cast<const float4*>(scores + (size_t)b * S_ + q * 1024);
    float4* ap = reinterpret_cast<float4*>(attn_out + (size_t)b * S_ + q * 1024);
    float4 sv = sp[t];
    float4 av;
    av.x = __expf(sv.x - mb) * inv_l;
    av.y = __expf(sv.y - mb) * inv_l;
    av.z = __expf(sv.z - mb) * inv_l;
    av.w = __expf(sv.w - mb) * inv_l;
    ap[t] = av;
}

// out[b,i] = tanh(dot(concat[b,:], Cw[i,:]) + Cb[i])
__global__ __launch_bounds__(256) void out_gemm(const float* __restrict__ concat,
                                                const float* __restrict__ Cw,
                                                const float* __restrict__ Cb,
                                                float* __restrict__ out) {
    int w = threadIdx.x >> 6, lane = threadIdx.x & 63;
    int i = blockIdx.x;
    const float4* wr = reinterpret_cast<const float4*>(Cw + (size_t)i * 2048);
    float4 wv[8];
    #pragma unroll
    for (int k = 0; k < 8; ++k) wv[k] = wr[lane + k * 64];
    float bias = Cb[i];
    #pragma unroll
    for (int bb = 0; bb < 8; ++bb) {
        int b = w * 8 + bb;
        const float4* cr = reinterpret_cast<const float4*>(concat + (size_t)b * 2048);
        float s = 0.f;
        #pragma unroll
        for (int k = 0; k < 8; ++k) {
            float4 c = cr[lane + k * 64];
            s += c.x * wv[k].x + c.y * wv[k].y + c.z * wv[k].z + c.w * wv[k].w;
        }
        s = wave_reduce_sum(s);
        if (lane == 0) out[(size_t)b * H_ + i] = tanhf(s + bias);
    }
}

extern "C" void kernel_launch(void* const* d_in, const int* in_sizes, int n_in,
                              void* d_out, int out_size, void* d_ws, size_t ws_size,
                              hipStream_t stream) {
    const float* hs  = (const float*)d_in[0];   // [B,1,H]
    const float* enc = (const float*)d_in[1];   // [B,S,H]
    const float* A_w = (const float*)d_in[2];   // [H,H]
    const float* A_b = (const float*)d_in[3];   // [H]
    const float* C_w = (const float*)d_in[4];   // [H,2H]
    const float* C_b = (const float*)d_in[5];   // [H]

    float* out      = (float*)d_out;            // [B,H] first
    float* attn_out = out + B_ * H_;            // then [B,S,1]

    // workspace layout (floats)
    float* ws       = (float*)d_ws;
    float* concat   = ws;                                   // [B][2048]: h1 | ctx
    float* h2       = ws + (size_t)B_ * 2048;               // [B][1024]
    float* scores   = h2 + (size_t)B_ * H_;                 // [B][S]
    float* partials = scores + (size_t)B_ * S_;             // [B][NBLK][H+2]

    gemv_aw<<<(B_ * H_) / 32, 256, 0, stream>>>(hs, H_, A_w, A_b, concat, 2048);
    gemv_aw<<<(B_ * H_) / 32, 256, 0, stream>>>(concat, 2048, A_w, A_b, h2, H_);
    attn_pass1<<<B_ * NBLK, 256, 0, stream>>>(enc, h2, scores, partials);
    attn_reduce<<<B_ * 4, 256, 0, stream>>>(partials, concat, scores, attn_out);
    out_gemm<<<H_, 256, 0, stream>>>(concat, C_w, C_b, out);
}